// Round 23
// baseline (142.102 us; speedup 1.0000x reference)
//
#include <hip/hip_runtime.h>

#define HW 28
#define NPIX 784   // 28*28
#define NIMG 64
#define MAXD2 1459 // d2 <= 2*27^2 = 1458
#define MAXREC 5504  // 783 * 7 worst case

// packed dx/dy (+1, 2 bits each) for {-1,0},{1,0},{0,-1},{0,1},
// {-1,-1},{-1,1},{1,-1},{1,1}; first 4 = 4-connectivity
#define DXPK 41048u
#define DYPK 34949u

// ---------------------------------------------------------------------------
// Kernel 1: distance-sort constants (counting sort, packed j|d2<<16) +
// per-image sums + x transpose, one dispatch. (r20 version — the canonical-
// table variant of r22 was timing-neutral with worse absmax.)
// ---------------------------------------------------------------------------
__global__ void consts_sums_kernel(unsigned int* __restrict__ TPK,
                                   const float* __restrict__ x,
                                   float* __restrict__ sums,
                                   float* __restrict__ xT) {
    int tid = threadIdx.x;
    if (blockIdx.x >= NPIX) {
        int m = blockIdx.x - NPIX;
        const float* xr = x + m * NPIX;
        float acc = 0.f;
        for (int j = tid; j < NPIX; j += 256) {
            float v = xr[j];
            xT[j * NIMG + m] = v;
            acc += v;
        }
        for (int off = 32; off > 0; off >>= 1) acc += __shfl_down(acc, off, 64);
        __shared__ float red[4];
        int lane = tid & 63, w = tid >> 6;
        if (lane == 0) red[w] = acc;
        __syncthreads();
        if (tid == 0) sums[m] = red[0] + red[1] + red[2] + red[3];
        return;
    }
    __shared__ int cnt[MAXD2];
    __shared__ int d2v[NPIX];
    __shared__ int wtot[4];
    int i = blockIdx.x;
    for (int b = tid; b < MAXD2; b += 256) cnt[b] = 0;
    __syncthreads();
    int ii = i / HW, ij = i % HW;
    for (int j = tid; j < NPIX; j += 256) {
        int di = ii - j / HW, dj = ij - j % HW;
        int d = di * di + dj * dj;
        d2v[j] = d;
        atomicAdd(&cnt[d], 1);
    }
    __syncthreads();
    int b0 = tid * 6;
    int lc[6];
    int s0 = 0;
    #pragma unroll
    for (int t = 0; t < 6; ++t) {
        int b = b0 + t;
        lc[t] = (b < MAXD2) ? cnt[b] : 0;
        s0 += lc[t];
    }
    int lane = tid & 63, wv = tid >> 6;
    int v = s0;
    for (int off = 1; off < 64; off <<= 1) {
        int t2 = __shfl_up(v, off, 64);
        if (lane >= off) v += t2;
    }
    if (lane == 63) wtot[wv] = v;
    __syncthreads();
    int wadd = 0;
    for (int w2 = 0; w2 < wv; ++w2) wadd += wtot[w2];
    int run = wadd + v - s0;
    __syncthreads();
    #pragma unroll
    for (int t = 0; t < 6; ++t) {
        int b = b0 + t;
        if (b < MAXD2) { cnt[b] = run; run += lc[t]; }
    }
    __syncthreads();
    for (int j = tid; j < NPIX; j += 256) {
        int d = d2v[j];
        int slot = atomicAdd(&cnt[d], 1);
        TPK[i * NPIX + slot] = (unsigned)j | ((unsigned)d << 16);
    }
}

// ---------------------------------------------------------------------------
// Kernel 2: DTM, transposed — one WAVE (block) per pixel, one lane per image.
// ---------------------------------------------------------------------------
__global__ void __launch_bounds__(64) dtm_kernel(const unsigned int* __restrict__ TPK,
                                                 const float* __restrict__ xT,
                                                 const float* __restrict__ sums,
                                                 float* __restrict__ F) {
    int lane = threadIdx.x;
    int i = blockIdx.x;
    float s = sums[lane];
    float bound1 = 0.05f * s, bound2 = 0.2f * s;
    const unsigned int* tp = TPK + (size_t)i * NPIX;
    float cum = 0.f, acc1 = 0.f, acc2 = 0.f;
    for (int t0 = 0; t0 < NPIX; t0 += 8) {   // 784 % 8 == 0
        unsigned int e[8];
        #pragma unroll
        for (int u = 0; u < 8; ++u) e[u] = tp[t0 + u];     // wave-uniform
        float w[8];
        #pragma unroll
        for (int u = 0; u < 8; ++u) w[u] = xT[(e[u] & 0xffffu) * NIMG + lane];
        #pragma unroll
        for (int u = 0; u < 8; ++u) {
            float d2 = (float)(e[u] >> 16);
            float ce = cum;
            cum += w[u];
            acc1 += fminf(fmaxf(bound1 - ce, 0.f), w[u]) * d2;
            acc2 += fminf(fmaxf(bound2 - ce, 0.f), w[u]) * d2;
        }
        if (__ballot(cum < bound2) == 0ull) break;  // all lanes done
    }
    F[0 * NIMG * NPIX + lane * NPIX + i] = sqrtf(acc1 / bound1);
    F[1 * NIMG * NPIX + lane * NPIX + i] = sqrtf(acc2 / bound2);
}

// ---------------------------------------------------------------------------
// Kernel 3: fused RANK + UF (basin decomposition) + LANDSCAPE.
// 1024 threads (4 waves/SIMD). NEW: P5 + landscape are WAVE-0-LOCAL with
// ZERO barriers — comp[] in P5 is only touched by wave 0 (same-wave LDS
// ordering suffices), the flatten runs on wave 0 (13 iters x ~3 cndmasks),
// and the landscape (tid<32) follows barrier-free. Waves 1..15 exit after
// P4. This removes ~20 full-block barrier rendezvous (the unmodeled bulk
// of uf_land's 40 µs at 16 waves).
// ---------------------------------------------------------------------------
template<int NN>   // NN = 4 (dir 0) or 8 (dir 1)
__device__ int uf_basin_run(const int* posA, const int* ordA,
                            int* bas, unsigned int* pb, int* comp,
                            int* recs, int* pairsI, int* wtot16) {
    const int tid = threadIdx.x;
    const int lane = tid & 63, wv = tid >> 6;   // wv in [0,16)

    // ---- P2: steepest-descent forest ----
    for (int s = tid; s < NPIX; s += 1024) {
        int si = s / HW, sj = s % HW;
        int bestPos = posA[s], best = s;
        #pragma unroll
        for (int o = 0; o < NN; ++o) {
            int dx = ((DXPK >> (2 * o)) & 3) - 1;
            int dy = ((DYPK >> (2 * o)) & 3) - 1;
            int ui = si + dx, uj = sj + dy;
            if ((unsigned)ui < (unsigned)HW && (unsigned)uj < (unsigned)HW) {
                int u = ui * HW + uj;
                int pu = posA[u];
                if (pu < bestPos) { bestPos = pu; best = u; }
            }
        }
        bas[s] = best;
    }
    __syncthreads();

    // ---- P3: pointer jumping with convergence early-exit ----
    for (int it = 0; it < 10; ++it) {
        int changed = 0;
        for (int s = tid; s < NPIX; s += 1024) {
            int b = bas[s];
            int bb = bas[b];
            if (bb != b) { bas[s] = bb; changed = 1; }
        }
        if (__syncthreads_count(changed) == 0) break;
    }

    // ---- pack (pos<<10 | bas) for single-gather P4 ----
    for (int s = tid; s < NPIX; s += 1024)
        pb[s] = ((unsigned)posA[s] << 10) | (unsigned)bas[s];
    __syncthreads();

    // ---- P4: candidate records in rank order (single pass, r = tid) ----
    int nrec = 0;
    {
        int r = tid;
        int cnt = 0;
        int myr[NN - 1];
        int got[NN - 1];
        #pragma unroll
        for (int t = 0; t < NN - 1; ++t) { got[t] = -1; myr[t] = 0; }
        if (r > 0 && r < NPIX) {
            int v = ordA[r];
            int vi = v / HW, vj = v % HW;
            int pivot = (int)(pb[v] & 1023u);
            #pragma unroll
            for (int o = 0; o < NN; ++o) {
                int dx = ((DXPK >> (2 * o)) & 3) - 1;
                int dy = ((DYPK >> (2 * o)) & 3) - 1;
                int ui = vi + dx, uj = vj + dy;
                if ((unsigned)ui < (unsigned)HW && (unsigned)uj < (unsigned)HW) {
                    int u = ui * HW + uj;
                    unsigned e = pb[u];
                    if ((int)(e >> 10) < r) {
                        int b = (int)(e & 1023u);
                        bool dup = (b == pivot);
                        #pragma unroll
                        for (int t = 0; t < NN - 1; ++t) dup = dup || (got[t] == b);
                        if (!dup) {
                            #pragma unroll
                            for (int t = 0; t < NN - 1; ++t)
                                if (t == cnt) { got[t] = b; myr[t] = (v << 20) | (pivot << 10) | b; }
                            cnt++;
                        }
                    }
                }
            }
        }
        // block-wide exclusive prefix of cnt (16 wave partials)
        int p = cnt;
        for (int off = 1; off < 64; off <<= 1) {
            int t2 = __shfl_up(p, off, 64);
            if (lane >= off) p += t2;
        }
        if (lane == 63) wtot16[wv] = p;
        __syncthreads();
        int wadd = 0;
        for (int w2 = 0; w2 < wv; ++w2) wadd += wtot16[w2];
        int tot = 0;
        #pragma unroll
        for (int w2 = 0; w2 < 16; ++w2) tot += wtot16[w2];
        int excl = wadd + p - cnt;
        #pragma unroll
        for (int t = 0; t < NN - 1; ++t)
            if (t < cnt) recs[excl + t] = myr[t];
        nrec = tot;
        __syncthreads();   // recs visible to wave 0
    }

    // ---- P5: wave-0-only ballot-driven UF — ZERO barriers ----
    int k = 0;
    if (wv == 0) {
        for (int base = 0; base < nrec; base += 64) {
            int idx = base + lane;
            int rec = (idx < nrec) ? recs[idx] : 0;
            int pa = (rec >> 10) & 1023, pbn = rec & 1023;
            int ka = 0, kb = 0;
            if (idx < nrec) { ka = comp[pa]; kb = comp[pbn]; }
            int remSrc = 0, remDst = 0;   // lane-distributed remap entries
            int nrem = 0;
            for (;;) {
                unsigned long long d = __ballot(ka != kb);
                if (d == 0ull) break;
                int i = (int)__ffsll((long long)d) - 1;   // lowest = lowest rank
                int sA = __builtin_amdgcn_readlane(ka, i);
                int sB = __builtin_amdgcn_readlane(kb, i);
                int w = min(sA, sB), l = max(sA, sB);     // uniform scalars
                int sv = __builtin_amdgcn_readlane(rec, i) >> 20;
                if (lane == 0) pairsI[k] = (l & 1023) | (sv << 10);
                k++;
                ka = (ka == l) ? w : ka;
                kb = (kb == l) ? w : kb;
                if (lane == nrem) { remSrc = l; remDst = w; }  // "writelane"
                nrem++;
                if (nrem == 63) {              // overflow guard (rare)
                    for (int s = lane; s < NPIX; s += 64) {
                        int cv = comp[s], c0 = cv;
                        for (int e = 0; e < nrem; ++e) {
                            int rs = __builtin_amdgcn_readlane(remSrc, e);
                            int rd = __builtin_amdgcn_readlane(remDst, e);
                            cv = (cv == rs) ? rd : cv;
                        }
                        if (cv != c0) comp[s] = cv;
                    }
                    if (idx < nrec) { ka = comp[pa]; kb = comp[pbn]; }
                    nrem = 0;
                }
            }
            if (nrem > 0 && base + 64 < nrec) {   // flatten (skip last chunk)
                for (int s = lane; s < NPIX; s += 64) {
                    int cv = comp[s], c0 = cv;
                    for (int e = 0; e < nrem; ++e) {
                        int rs = __builtin_amdgcn_readlane(remSrc, e);
                        int rd = __builtin_amdgcn_readlane(remDst, e);
                        cv = (cv == rs) ? rd : cv;
                    }
                    if (cv != c0) comp[s] = cv;
                }
            }
        }
    }
    return k;   // valid in wave 0 only (landscape runs on tid<32)
}

__global__ void __launch_bounds__(1024) uf_land_kernel(const float* __restrict__ F,
                                                       float* __restrict__ LAM1,
                                                       float* __restrict__ LAM2) {
    __shared__ int posA[NPIX], ordA[NPIX], bas[NPIX], comp[NPIX], pairsI[NPIX];
    __shared__ unsigned int pbArr[NPIX];  // packed (pos,bas) for P4
    __shared__ alignas(16) unsigned long long key64[NPIX];  // rank keys
    __shared__ float fv[NPIX];
    __shared__ int recs[MAXREC];
    __shared__ int wtot16[16];
    int tid = threadIdx.x;
    int task = blockIdx.x;
    int feat = task >> 7;
    int dir = (task >> 6) & 1;
    int m = task & 63;
    const float* fr = F + feat * NIMG * NPIX + m * NPIX;

    // load values + precomputed packed u64 sort keys (values >= 0: bits
    // monotone; dir==1 uses ~bits so both dirs are the same ascending cmp)
    for (int j = tid; j < NPIX; j += 1024) {
        float f = fr[j];
        fv[j] = f;
        unsigned int b = __float_as_uint(f);
        if (dir) b = ~b;
        key64[j] = ((unsigned long long)b << 10) | (unsigned)j;
    }
    __syncthreads();

    // ---- fused rank: 16 waves, 1 row/thread (r20 layout — measured best) ----
    if (tid < NPIX) {
        unsigned long long pki = key64[tid];
        int rank = 0;
        const ulonglong2* k2 = (const ulonglong2*)key64;
        for (int c = 0; c < NPIX / 2; ++c) {
            ulonglong2 kv = k2[c];
            rank += (int)(kv.x < pki) + (int)(kv.y < pki);
        }
        posA[tid] = rank;
        ordA[rank] = tid;
    }
    __syncthreads();
    for (int s = tid; s < NPIX; s += 1024) comp[s] = (posA[s] << 10) | s;
    // (comp init needs no barrier before P2: P2 reads only posA; comp is
    //  first read in P5 by wave 0, after the P4 barrier)

    int k;
    if (dir == 0) k = uf_basin_run<4>(posA, ordA, bas, pbArr, comp, recs,
                                      pairsI, wtot16);
    else          k = uf_basin_run<8>(posA, ordA, bas, pbArr, comp, recs,
                                      pairsI, wtot16);

    // ---- fused landscape (wave-0, barrier-free: pairsI written by wave 0) ----
    if (tid < 32) {
        int t = tid;
        float start = (feat == 0) ? 0.f : 1.f;
        float end   = (feat == 0) ? 7.f : 8.f;
        float tv = start + (end - start) * ((float)t / 31.f);
        float v0 = 0.f, v1 = 0.f, v2 = 0.f;
        for (int p = 0; p < k; ++p) {
            int pi = pairsI[p];                   // same addr all lanes
            float fb = fv[pi & 1023], fd = fv[pi >> 10];
            float bb = dir ? fd : fb;
            float dd = dir ? fb : fd;
            float tent = fmaxf(fminf(tv - bb, dd - tv), 0.f);
            if (tent > v0)      { v2 = v1; v1 = v0; v0 = tent; }
            else if (tent > v1) { v2 = v1; v1 = tent; }
            else if (tent > v2) { v2 = tent; }
        }
        if (feat == 0) {
            float* lam = LAM1 + m * 128 + dir * 64;
            lam[0 * 32 + t] = v0;
            lam[1 * 32 + t] = v1;
        } else {
            float* lam = LAM2 + m * 192 + dir * 96;
            lam[0 * 32 + t] = v0;
            lam[1 * 32 + t] = v1;
            lam[2 * 32 + t] = v2;
        }
    }
}

// ---------------------------------------------------------------------------
// Kernel 4: MLP head. One block (64 threads) per image.
// ---------------------------------------------------------------------------
__global__ void mlp_kernel(const float* __restrict__ LAM1, const float* __restrict__ LAM2,
                           const float* __restrict__ w1, const float* __restrict__ b1,
                           const float* __restrict__ w2, const float* __restrict__ b2,
                           const float* __restrict__ wf, const float* __restrict__ bf,
                           float* __restrict__ out) {
    __shared__ float xc[64];
    int m = blockIdx.x;
    int n = threadIdx.x;
    if (n < 32) {
        float acc = b1[n];
        const float* l = LAM1 + m * 128;
        for (int c = 0; c < 128; ++c) acc += w1[n * 128 + c] * l[c];
        xc[n] = fmaxf(acc, 0.f);
    } else {
        int n2 = n - 32;
        float acc = b2[n2];
        const float* l = LAM2 + m * 192;
        for (int c = 0; c < 192; ++c) acc += w2[n2 * 192 + c] * l[c];
        xc[n] = fmaxf(acc, 0.f);
    }
    __syncthreads();
    if (n < 10) {
        float acc = bf[n];
        for (int c = 0; c < 64; ++c) acc += wf[n * 64 + c] * xc[c];
        out[m * 10 + n] = acc;
    }
}

extern "C" void kernel_launch(void* const* d_in, const int* in_sizes, int n_in,
                              void* d_out, int out_size, void* d_ws, size_t ws_size,
                              hipStream_t stream) {
    const float* x  = (const float*)d_in[0];
    const float* w1 = (const float*)d_in[1];
    const float* b1 = (const float*)d_in[2];
    const float* w2 = (const float*)d_in[3];
    const float* b2 = (const float*)d_in[4];
    const float* wf = (const float*)d_in[5];
    const float* bf = (const float*)d_in[6];
    float* out = (float*)d_out;

    char* ws = (char*)d_ws;
    size_t off = 0;
    unsigned int* TPK = (unsigned int*)(ws + off); off += (size_t)NPIX * NPIX * 4;
    float* XT   = (float*)(ws + off); off += (size_t)NPIX * NIMG * 4;
    float* SUMS = (float*)(ws + off); off += 256;
    float* F    = (float*)(ws + off); off += (size_t)2 * NIMG * NPIX * 4;
    float* LAM1 = (float*)(ws + off); off += (size_t)NIMG * 128 * 4;
    float* LAM2 = (float*)(ws + off); off += (size_t)NIMG * 192 * 4;

    consts_sums_kernel<<<NPIX + NIMG, 256, 0, stream>>>(TPK, x, SUMS, XT);
    dtm_kernel<<<NPIX, 64, 0, stream>>>(TPK, XT, SUMS, F);
    uf_land_kernel<<<256, 1024, 0, stream>>>(F, LAM1, LAM2);
    mlp_kernel<<<NIMG, 64, 0, stream>>>(LAM1, LAM2, w1, b1, w2, b2, wf, bf, out);
}

// Round 24
// 122.555 us; speedup vs baseline: 1.1595x; 1.1595x over previous
//
#include <hip/hip_runtime.h>

#define HW 28
#define NPIX 784   // 28*28
#define NIMG 64
#define MAXD2 1459 // d2 <= 2*27^2 = 1458
#define MAXREC 5504  // 783 * 7 worst case

// packed dx/dy (+1, 2 bits each) for {-1,0},{1,0},{0,-1},{0,1},
// {-1,-1},{-1,1},{1,-1},{1,1}; first 4 = 4-connectivity
#define DXPK 41048u
#define DYPK 34949u

// ---------------------------------------------------------------------------
// Kernel 1: distance-sort constants (counting sort, packed j|d2<<16) +
// per-image sums + x transpose, one dispatch. (r20 measured-best config.)
// ---------------------------------------------------------------------------
__global__ void consts_sums_kernel(unsigned int* __restrict__ TPK,
                                   const float* __restrict__ x,
                                   float* __restrict__ sums,
                                   float* __restrict__ xT) {
    int tid = threadIdx.x;
    if (blockIdx.x >= NPIX) {
        int m = blockIdx.x - NPIX;
        const float* xr = x + m * NPIX;
        float acc = 0.f;
        for (int j = tid; j < NPIX; j += 256) {
            float v = xr[j];
            xT[j * NIMG + m] = v;
            acc += v;
        }
        for (int off = 32; off > 0; off >>= 1) acc += __shfl_down(acc, off, 64);
        __shared__ float red[4];
        int lane = tid & 63, w = tid >> 6;
        if (lane == 0) red[w] = acc;
        __syncthreads();
        if (tid == 0) sums[m] = red[0] + red[1] + red[2] + red[3];
        return;
    }
    __shared__ int cnt[MAXD2];
    __shared__ int d2v[NPIX];
    __shared__ int wtot[4];
    int i = blockIdx.x;
    for (int b = tid; b < MAXD2; b += 256) cnt[b] = 0;
    __syncthreads();
    int ii = i / HW, ij = i % HW;
    for (int j = tid; j < NPIX; j += 256) {
        int di = ii - j / HW, dj = ij - j % HW;
        int d = di * di + dj * dj;
        d2v[j] = d;
        atomicAdd(&cnt[d], 1);
    }
    __syncthreads();
    int b0 = tid * 6;
    int lc[6];
    int s0 = 0;
    #pragma unroll
    for (int t = 0; t < 6; ++t) {
        int b = b0 + t;
        lc[t] = (b < MAXD2) ? cnt[b] : 0;
        s0 += lc[t];
    }
    int lane = tid & 63, wv = tid >> 6;
    int v = s0;
    for (int off = 1; off < 64; off <<= 1) {
        int t2 = __shfl_up(v, off, 64);
        if (lane >= off) v += t2;
    }
    if (lane == 63) wtot[wv] = v;
    __syncthreads();
    int wadd = 0;
    for (int w2 = 0; w2 < wv; ++w2) wadd += wtot[w2];
    int run = wadd + v - s0;
    __syncthreads();
    #pragma unroll
    for (int t = 0; t < 6; ++t) {
        int b = b0 + t;
        if (b < MAXD2) { cnt[b] = run; run += lc[t]; }
    }
    __syncthreads();
    for (int j = tid; j < NPIX; j += 256) {
        int d = d2v[j];
        int slot = atomicAdd(&cnt[d], 1);
        TPK[i * NPIX + slot] = (unsigned)j | ((unsigned)d << 16);
    }
}

// ---------------------------------------------------------------------------
// Kernel 2: DTM, transposed — one WAVE (block) per pixel, one lane per image.
// ---------------------------------------------------------------------------
__global__ void __launch_bounds__(64) dtm_kernel(const unsigned int* __restrict__ TPK,
                                                 const float* __restrict__ xT,
                                                 const float* __restrict__ sums,
                                                 float* __restrict__ F) {
    int lane = threadIdx.x;
    int i = blockIdx.x;
    float s = sums[lane];
    float bound1 = 0.05f * s, bound2 = 0.2f * s;
    const unsigned int* tp = TPK + (size_t)i * NPIX;
    float cum = 0.f, acc1 = 0.f, acc2 = 0.f;
    for (int t0 = 0; t0 < NPIX; t0 += 8) {   // 784 % 8 == 0
        unsigned int e[8];
        #pragma unroll
        for (int u = 0; u < 8; ++u) e[u] = tp[t0 + u];     // wave-uniform
        float w[8];
        #pragma unroll
        for (int u = 0; u < 8; ++u) w[u] = xT[(e[u] & 0xffffu) * NIMG + lane];
        #pragma unroll
        for (int u = 0; u < 8; ++u) {
            float d2 = (float)(e[u] >> 16);
            float ce = cum;
            cum += w[u];
            acc1 += fminf(fmaxf(bound1 - ce, 0.f), w[u]) * d2;
            acc2 += fminf(fmaxf(bound2 - ce, 0.f), w[u]) * d2;
        }
        if (__ballot(cum < bound2) == 0ull) break;  // all lanes done
    }
    F[0 * NIMG * NPIX + lane * NPIX + i] = sqrtf(acc1 / bound1);
    F[1 * NIMG * NPIX + lane * NPIX + i] = sqrtf(acc2 / bound2);
}

// ---------------------------------------------------------------------------
// Kernel 3: fused RANK + UF (basin decomposition) + LANDSCAPE.
// 1024 threads (4 waves/SIMD). r20 measured-best structure: barriered P5
// with 1024-thread flatten (r23 lesson: serializing the flatten onto wave 0
// to avoid barriers cost +16 µs — barriers here buy a 16x parallel flatten).
// ---------------------------------------------------------------------------
template<int NN>   // NN = 4 (dir 0) or 8 (dir 1)
__device__ int uf_basin_run(const int* posA, const int* ordA,
                            int* bas, unsigned int* pb, int* comp,
                            int* recs, int* pairsI,
                            int2* mergeLDS, int* shInts, int* wtot16) {
    const int tid = threadIdx.x;
    const int lane = tid & 63, wv = tid >> 6;   // wv in [0,16)

    // ---- P2: steepest-descent forest ----
    for (int s = tid; s < NPIX; s += 1024) {
        int si = s / HW, sj = s % HW;
        int bestPos = posA[s], best = s;
        #pragma unroll
        for (int o = 0; o < NN; ++o) {
            int dx = ((DXPK >> (2 * o)) & 3) - 1;
            int dy = ((DYPK >> (2 * o)) & 3) - 1;
            int ui = si + dx, uj = sj + dy;
            if ((unsigned)ui < (unsigned)HW && (unsigned)uj < (unsigned)HW) {
                int u = ui * HW + uj;
                int pu = posA[u];
                if (pu < bestPos) { bestPos = pu; best = u; }
            }
        }
        bas[s] = best;
    }
    __syncthreads();

    // ---- P3: pointer jumping with convergence early-exit ----
    for (int it = 0; it < 10; ++it) {
        int changed = 0;
        for (int s = tid; s < NPIX; s += 1024) {
            int b = bas[s];
            int bb = bas[b];
            if (bb != b) { bas[s] = bb; changed = 1; }
        }
        if (__syncthreads_count(changed) == 0) break;
    }

    // ---- pack (pos<<10 | bas) for single-gather P4 ----
    for (int s = tid; s < NPIX; s += 1024)
        pb[s] = ((unsigned)posA[s] << 10) | (unsigned)bas[s];
    __syncthreads();

    // ---- P4: candidate records in rank order (single pass, r = tid) ----
    int nrec = 0;
    {
        int r = tid;
        int cnt = 0;
        int myr[NN - 1];
        int got[NN - 1];
        #pragma unroll
        for (int t = 0; t < NN - 1; ++t) { got[t] = -1; myr[t] = 0; }
        if (r > 0 && r < NPIX) {
            int v = ordA[r];
            int vi = v / HW, vj = v % HW;
            int pivot = (int)(pb[v] & 1023u);
            #pragma unroll
            for (int o = 0; o < NN; ++o) {
                int dx = ((DXPK >> (2 * o)) & 3) - 1;
                int dy = ((DYPK >> (2 * o)) & 3) - 1;
                int ui = vi + dx, uj = vj + dy;
                if ((unsigned)ui < (unsigned)HW && (unsigned)uj < (unsigned)HW) {
                    int u = ui * HW + uj;
                    unsigned e = pb[u];
                    if ((int)(e >> 10) < r) {
                        int b = (int)(e & 1023u);
                        bool dup = (b == pivot);
                        #pragma unroll
                        for (int t = 0; t < NN - 1; ++t) dup = dup || (got[t] == b);
                        if (!dup) {
                            #pragma unroll
                            for (int t = 0; t < NN - 1; ++t)
                                if (t == cnt) { got[t] = b; myr[t] = (v << 20) | (pivot << 10) | b; }
                            cnt++;
                        }
                    }
                }
            }
        }
        // block-wide exclusive prefix of cnt (16 wave partials)
        int p = cnt;
        for (int off = 1; off < 64; off <<= 1) {
            int t2 = __shfl_up(p, off, 64);
            if (lane >= off) p += t2;
        }
        if (lane == 63) wtot16[wv] = p;
        __syncthreads();
        int wadd = 0;
        for (int w2 = 0; w2 < wv; ++w2) wadd += wtot16[w2];
        int tot = 0;
        #pragma unroll
        for (int w2 = 0; w2 < 16; ++w2) tot += wtot16[w2];
        int excl = wadd + p - cnt;
        #pragma unroll
        for (int t = 0; t < NN - 1; ++t)
            if (t < cnt) recs[excl + t] = myr[t];
        nrec = tot;
        __syncthreads();
    }

    // ---- P5: ballot-driven serial UF (wave 0), block-wide flatten ----
    int k = 0;
    for (int base = 0; base < nrec; base += 64) {
        int nrem = 0;
        if (wv == 0) {
            int idx = base + lane;
            int rec = (idx < nrec) ? recs[idx] : 0;
            int pa = (rec >> 10) & 1023, pbn = rec & 1023;
            int ka = 0, kb = 0;
            if (idx < nrec) { ka = comp[pa]; kb = comp[pbn]; }
            for (;;) {
                unsigned long long d = __ballot(ka != kb);
                if (d == 0ull) break;
                int i = (int)__ffsll((long long)d) - 1;   // lowest lane = lowest rank
                int sA = __builtin_amdgcn_readlane(ka, i);
                int sB = __builtin_amdgcn_readlane(kb, i);
                int w = min(sA, sB), l = max(sA, sB);     // uniform scalars
                int sv = __builtin_amdgcn_readlane(rec, i) >> 20;
                if (lane == 0) {
                    pairsI[k] = (l & 1023) | (sv << 10);
                    mergeLDS[nrem] = make_int2(l, w);
                }
                k++;
                ka = (ka == l) ? w : ka;
                kb = (kb == l) ? w : kb;
                nrem++;
                if (nrem == 63) {              // overflow guard (rare): wave-0 flatten
                    for (int s = lane; s < NPIX; s += 64) {
                        int cv = comp[s], c0 = cv;
                        for (int e = 0; e < nrem; ++e) {
                            int2 me = mergeLDS[e];
                            cv = (cv == me.x) ? me.y : cv;
                        }
                        if (cv != c0) comp[s] = cv;
                    }
                    if (idx < nrec) { ka = comp[pa]; kb = comp[pbn]; }
                    nrem = 0;
                }
            }
            if (lane == 0) shInts[0] = nrem;
        }
        __syncthreads();
        int nr = shInts[0];
        if (nr > 0) {                          // flatten with all 1024 threads
            for (int s = tid; s < NPIX; s += 1024) {
                int cv = comp[s], c0 = cv;
                for (int e = 0; e < nr; ++e) {
                    int2 me = mergeLDS[e];
                    cv = (cv == me.x) ? me.y : cv;
                }
                if (cv != c0) comp[s] = cv;
            }
        }
        __syncthreads();
    }
    if (tid == 0) shInts[1] = k;
    __syncthreads();
    return shInts[1];
}

__global__ void __launch_bounds__(1024) uf_land_kernel(const float* __restrict__ F,
                                                       float* __restrict__ LAM1,
                                                       float* __restrict__ LAM2) {
    __shared__ int posA[NPIX], ordA[NPIX], bas[NPIX], comp[NPIX], pairsI[NPIX];
    __shared__ unsigned int pbArr[NPIX];  // packed (pos,bas) for P4
    __shared__ alignas(16) unsigned long long key64[NPIX];  // rank keys
    __shared__ float fv[NPIX];
    __shared__ int recs[MAXREC];
    __shared__ int2 mergeLDS[64];
    __shared__ int shInts[2];
    __shared__ int wtot16[16];
    int tid = threadIdx.x;
    int task = blockIdx.x;
    int feat = task >> 7;
    int dir = (task >> 6) & 1;
    int m = task & 63;
    const float* fr = F + feat * NIMG * NPIX + m * NPIX;

    // load values + precomputed packed u64 sort keys (values >= 0: bits
    // monotone; dir==1 uses ~bits so both dirs are the same ascending cmp)
    for (int j = tid; j < NPIX; j += 1024) {
        float f = fr[j];
        fv[j] = f;
        unsigned int b = __float_as_uint(f);
        if (dir) b = ~b;
        key64[j] = ((unsigned long long)b << 10) | (unsigned)j;
    }
    __syncthreads();

    // ---- fused rank: b128 reads of prepacked u64 keys, 1 cmp each ----
    if (tid < NPIX) {
        unsigned long long pki = key64[tid];
        int rank = 0;
        const ulonglong2* k2 = (const ulonglong2*)key64;
        for (int c = 0; c < NPIX / 2; ++c) {
            ulonglong2 kv = k2[c];
            rank += (int)(kv.x < pki) + (int)(kv.y < pki);
        }
        posA[tid] = rank;
        ordA[rank] = tid;
    }
    __syncthreads();
    for (int s = tid; s < NPIX; s += 1024) comp[s] = (posA[s] << 10) | s;
    // (comp init needs no barrier before P2: P2 reads only posA)

    int k;
    if (dir == 0) k = uf_basin_run<4>(posA, ordA, bas, pbArr, comp, recs, pairsI,
                                      mergeLDS, shInts, wtot16);
    else          k = uf_basin_run<8>(posA, ordA, bas, pbArr, comp, recs, pairsI,
                                      mergeLDS, shInts, wtot16);

    // ---- fused landscape: top-3 tents directly from pairsI (broadcast) ----
    if (tid < 32) {
        int t = tid;
        float start = (feat == 0) ? 0.f : 1.f;
        float end   = (feat == 0) ? 7.f : 8.f;
        float tv = start + (end - start) * ((float)t / 31.f);
        float v0 = 0.f, v1 = 0.f, v2 = 0.f;
        for (int p = 0; p < k; ++p) {
            int pi = pairsI[p];                   // same addr all lanes
            float fb = fv[pi & 1023], fd = fv[pi >> 10];
            float bb = dir ? fd : fb;
            float dd = dir ? fb : fd;
            float tent = fmaxf(fminf(tv - bb, dd - tv), 0.f);
            if (tent > v0)      { v2 = v1; v1 = v0; v0 = tent; }
            else if (tent > v1) { v2 = v1; v1 = tent; }
            else if (tent > v2) { v2 = tent; }
        }
        if (feat == 0) {
            float* lam = LAM1 + m * 128 + dir * 64;
            lam[0 * 32 + t] = v0;
            lam[1 * 32 + t] = v1;
        } else {
            float* lam = LAM2 + m * 192 + dir * 96;
            lam[0 * 32 + t] = v0;
            lam[1 * 32 + t] = v1;
            lam[2 * 32 + t] = v2;
        }
    }
}

// ---------------------------------------------------------------------------
// Kernel 4: MLP head. One block (64 threads) per image.
// ---------------------------------------------------------------------------
__global__ void mlp_kernel(const float* __restrict__ LAM1, const float* __restrict__ LAM2,
                           const float* __restrict__ w1, const float* __restrict__ b1,
                           const float* __restrict__ w2, const float* __restrict__ b2,
                           const float* __restrict__ wf, const float* __restrict__ bf,
                           float* __restrict__ out) {
    __shared__ float xc[64];
    int m = blockIdx.x;
    int n = threadIdx.x;
    if (n < 32) {
        float acc = b1[n];
        const float* l = LAM1 + m * 128;
        for (int c = 0; c < 128; ++c) acc += w1[n * 128 + c] * l[c];
        xc[n] = fmaxf(acc, 0.f);
    } else {
        int n2 = n - 32;
        float acc = b2[n2];
        const float* l = LAM2 + m * 192;
        for (int c = 0; c < 192; ++c) acc += w2[n2 * 192 + c] * l[c];
        xc[n] = fmaxf(acc, 0.f);
    }
    __syncthreads();
    if (n < 10) {
        float acc = bf[n];
        for (int c = 0; c < 64; ++c) acc += wf[n * 64 + c] * xc[c];
        out[m * 10 + n] = acc;
    }
}

extern "C" void kernel_launch(void* const* d_in, const int* in_sizes, int n_in,
                              void* d_out, int out_size, void* d_ws, size_t ws_size,
                              hipStream_t stream) {
    const float* x  = (const float*)d_in[0];
    const float* w1 = (const float*)d_in[1];
    const float* b1 = (const float*)d_in[2];
    const float* w2 = (const float*)d_in[3];
    const float* b2 = (const float*)d_in[4];
    const float* wf = (const float*)d_in[5];
    const float* bf = (const float*)d_in[6];
    float* out = (float*)d_out;

    char* ws = (char*)d_ws;
    size_t off = 0;
    unsigned int* TPK = (unsigned int*)(ws + off); off += (size_t)NPIX * NPIX * 4;
    float* XT   = (float*)(ws + off); off += (size_t)NPIX * NIMG * 4;
    float* SUMS = (float*)(ws + off); off += 256;
    float* F    = (float*)(ws + off); off += (size_t)2 * NIMG * NPIX * 4;
    float* LAM1 = (float*)(ws + off); off += (size_t)NIMG * 128 * 4;
    float* LAM2 = (float*)(ws + off); off += (size_t)NIMG * 192 * 4;

    consts_sums_kernel<<<NPIX + NIMG, 256, 0, stream>>>(TPK, x, SUMS, XT);
    dtm_kernel<<<NPIX, 64, 0, stream>>>(TPK, XT, SUMS, F);
    uf_land_kernel<<<256, 1024, 0, stream>>>(F, LAM1, LAM2);
    mlp_kernel<<<NIMG, 64, 0, stream>>>(LAM1, LAM2, w1, b1, w2, b2, wf, bf, out);
}